// Round 6
// baseline (568.843 us; speedup 1.0000x reference)
//
#include <hip/hip_runtime.h>
#include <math.h>

#define B_ 32
#define L_ 4096
#define D_ 128
#define H_ 256
#define O_ 128
#define NROWS (B_*L_)          // 131072
#define O_ELEMS ((long)NROWS*O_)   // 16777216

typedef float f32x4_t __attribute__((ext_vector_type(4)));
typedef short bf16x8_t __attribute__((ext_vector_type(8)));
typedef unsigned short u16;

__device__ __forceinline__ u16 f2bf(float f){           // RNE f32 -> bf16 bits
  unsigned u = __float_as_uint(f);
  unsigned r = (u + 0x7FFFu + ((u >> 16) & 1u)) >> 16;
  return (u16)r;
}

__device__ __forceinline__ void split8(const float* v, bf16x8_t& hi, bf16x8_t& lo){
  #pragma unroll
  for (int j = 0; j < 8; j++){
    unsigned u = __float_as_uint(v[j]);
    hi[j] = (short)(u >> 16);                            // truncated high part (exact)
    lo[j] = (short)f2bf(v[j] - __uint_as_float(u & 0xFFFF0000u));
  }
}

// ---------------- LN1: x -> xln (xln aliases d_out o-region) ----------------
// v2: 2 rows/wave, float4/lane (16B), half-wave shuffle reduce.
__global__ __launch_bounds__(256) void k_ln1(const float* __restrict__ x,
    const float* __restrict__ g1, const float* __restrict__ b1, float* __restrict__ xln){
  int t = threadIdx.x;
  int half = t >> 5, hl = t & 31;                       // 8 half-waves per block
  long row = (long)blockIdx.x * 8 + half;
  const float* xr = x + row * D_;
  f32x4_t v = *(const f32x4_t*)(xr + hl * 4);
  float s  = v[0] + v[1] + v[2] + v[3];
  float sq = v[0]*v[0] + v[1]*v[1] + v[2]*v[2] + v[3]*v[3];
  #pragma unroll
  for (int m = 1; m < 32; m <<= 1){ s += __shfl_xor(s, m); sq += __shfl_xor(sq, m); }
  float mean = s * (1.0f / 128.0f);
  float var  = sq * (1.0f / 128.0f) - mean * mean;
  float rstd = rsqrtf(var + 1e-8f);
  f32x4_t gg = *(const f32x4_t*)(g1 + hl * 4);
  f32x4_t bb = *(const f32x4_t*)(b1 + hl * 4);
  f32x4_t o;
  #pragma unroll
  for (int j = 0; j < 4; j++) o[j] = (v[j] - mean) * rstd * gg[j] + bb[j];
  *(f32x4_t*)(xln + row * D_ + hl * 4) = o;
}

// ---------------- per-batch raw gram S_b = X_b^T X_b  (+ fused column sums) ----
// v2: 16 chunks of 256 rows (512 blocks = 2/CU), colsum fused from LDS tile.
__global__ __launch_bounds__(256, 2) void k_gram(const float* __restrict__ xln,
                                                 float* __restrict__ gram,
                                                 float* __restrict__ colsum){
  __shared__ float xs[64][128];
  int b = blockIdx.x >> 4, chunk = blockIdx.x & 15;     // 16 chunks of 256 rows
  const float* base = xln + ((long)b * L_ + (long)chunk * 256) * D_;
  int t = threadIdx.x;
  int dr = (t >> 4) * 8, ec = (t & 15) * 8;
  int cc = t & 127, rlo = (t >> 7) * 32;                // colsum split: 2 halves of rows
  float cs = 0.f;
  float acc[8][8];
  #pragma unroll
  for (int i = 0; i < 8; i++)
    #pragma unroll
    for (int j = 0; j < 8; j++) acc[i][j] = 0.f;
  for (int sub = 0; sub < 4; sub++){
    __syncthreads();
    const float* src = base + (long)sub * 64 * D_;
    #pragma unroll
    for (int i = 0; i < 8; i++){
      int idx = t + i * 256;                            // 2048 float4 = 64x128 floats
      ((f32x4_t*)&xs[0][0])[idx] = ((const f32x4_t*)src)[idx];
    }
    __syncthreads();
    for (int l = 0; l < 64; l++){
      float a[8], c[8];
      #pragma unroll
      for (int i = 0; i < 8; i++){ a[i] = xs[l][dr + i]; c[i] = xs[l][ec + i]; }
      #pragma unroll
      for (int i = 0; i < 8; i++)
        #pragma unroll
        for (int j = 0; j < 8; j++) acc[i][j] += a[i] * c[j];
    }
    for (int l = rlo; l < rlo + 32; l++) cs += xs[l][cc];
  }
  float* gb = gram + (long)b * D_ * D_;
  #pragma unroll
  for (int i = 0; i < 8; i++)
    #pragma unroll
    for (int j = 0; j < 8; j++)
      atomicAdd(&gb[(dr + i) * D_ + ec + j], acc[i][j]);
  atomicAdd(&colsum[b * D_ + cc], cs);
}

// ---------------- per-batch means and centered norms ----------------
__global__ void k_stats(const float* __restrict__ colsum, const float* __restrict__ gram,
                        float* __restrict__ means, float* __restrict__ norms){
  int b = blockIdx.x, d = threadIdx.x;
  float m = colsum[b * D_ + d] * (1.0f / (float)L_);
  float cov = gram[((long)b * D_ + d) * D_ + d] - (float)L_ * m * m;
  cov = fmaxf(cov, 0.f);
  means[b * D_ + d] = m;
  norms[b * D_ + d] = fmaxf(sqrtf(cov), 1e-8f);
}

// ---------------- mixed correlation (output 1) + degree vector ----------------
__global__ __launch_bounds__(128) void k_mixed(const float* __restrict__ gram,
    const float* __restrict__ means, const float* __restrict__ norms,
    const float* __restrict__ corr, const float* __restrict__ alpha_logit,
    float* __restrict__ mixed_out, float* __restrict__ deg){
  int d = blockIdx.x, e = threadIdx.x;
  float s = 0.f;
  for (int b = 0; b < B_; b++){
    float cov = gram[((long)b * D_ + d) * D_ + e]
              - (float)L_ * means[b * D_ + d] * means[b * D_ + e];
    s += cov / (norms[b * D_ + d] * norms[b * D_ + e]);
  }
  float dc = fminf(fmaxf(s * (1.0f / (float)B_), -1.f), 1.f);
  float learned = tanhf(0.5f * (corr[d * D_ + e] + corr[e * D_ + d]));
  float alpha = 1.f / (1.f + expf(-alpha_logit[0]));
  float mx = alpha * learned + (1.f - alpha) * dc;
  mixed_out[d * D_ + e] = mx;
  float a = (d == e) ? 0.f : mx;
  __shared__ float red[128];
  red[e] = a; __syncthreads();
  for (int st = 64; st > 0; st >>= 1){
    if (e < st) red[e] += red[e + st];
    __syncthreads();
  }
  if (e == 0) deg[d] = red[0];
}

// ---------------- Laplacian -> fragment-ordered bf16 hi/lo ----------------
__global__ __launch_bounds__(128) void k_lap(const float* __restrict__ mixed_out,
    const float* __restrict__ deg, u16* __restrict__ lapf_hi, u16* __restrict__ lapf_lo){
  int d = blockIdx.x, e = threadIdx.x;                  // Lap row d (k-index), col e
  float dis_d = rsqrtf(fmaxf(deg[d], 1e-8f));
  float dis_e = rsqrtf(fmaxf(deg[e], 1e-8f));
  float A = (d == e) ? 0.f : mixed_out[d * D_ + e];
  float lv = ((d == e) ? 1.f : 0.f) - dis_d * A * dis_e;
  lv = fminf(fmaxf(lv, -1.5f), 1.5f);
  // B-fragment position for mfma_f32_16x16x32_bf16: col=ct*16+(lane&15), k=kf*32+(lane>>4)*8+j
  int ct = e >> 4, llw = e & 15;
  int kf = d >> 5, g = (d >> 3) & 3, j = d & 7;
  long idx = (((long)(ct * 4 + kf)) * 64 + (g * 16 + llw)) * 8 + j;
  unsigned u = __float_as_uint(lv);
  lapf_hi[idx] = (u16)(u >> 16);
  lapf_lo[idx] = f2bf(lv - __uint_as_float(u & 0xFFFF0000u));
}

// ---------------- Wi / Wo -> fragment-ordered plain bf16 ----------------
__global__ void k_prepw(const float* __restrict__ Wi, const float* __restrict__ Wo,
                        u16* __restrict__ wif, u16* __restrict__ wof){
  int tid = blockIdx.x * 256 + threadIdx.x;             // 8192 total
  if (tid < 4096){                                      // Wi: ct(16) kf(4) lane(64)
    int lane = tid & 63, kf = (tid >> 6) & 3, ct = tid >> 8;
    int row = ct * 16 + (lane & 15);
    int k0 = kf * 32 + (lane >> 4) * 8;
    #pragma unroll
    for (int j = 0; j < 8; j++) wif[tid * 8 + j] = f2bf(Wi[row * D_ + k0 + j]);
  } else {                                              // Wo: ct(8) kf(8) lane(64)
    int t = tid - 4096;
    int lane = t & 63, kf = (t >> 6) & 7, ct = t >> 9;
    int row = ct * 16 + (lane & 15);
    int k0 = kf * 32 + (lane >> 4) * 8;
    #pragma unroll
    for (int j = 0; j < 8; j++) wof[t * 8 + j] = f2bf(Wo[row * H_ + k0 + j]);
  }
}

// ---------------- fused Cheb + proj + LN2/gelu + LN3 ----------------
// v2: 8.25 KB LDS/wave (union of Tst f32[16][132] and h bf16[16][264]);
//     Xst dropped (X re-read from global, LLC-resident, in phase E);
//     4 blocks/CU target.
__global__ __launch_bounds__(256, 4) void k_mega(
    const float* xln, float* out,                       // ALIAS (same buffer) - no restrict
    const u16* __restrict__ lapf_hi, const u16* __restrict__ lapf_lo,
    const u16* __restrict__ wif, const u16* __restrict__ wof,
    const float* __restrict__ bi, const float* __restrict__ bo,
    const float* __restrict__ g2, const float* __restrict__ b2,
    const float* __restrict__ g3, const float* __restrict__ b3,
    const float* __restrict__ chebw)
{
  __shared__ float smem[4][2112];                       // 8448 B per wave
  const int wave = threadIdx.x >> 6, lane = threadIdx.x & 63;
  const int ll = lane & 15, g = lane >> 4;
  float* Tst = &smem[wave][0];                          // T1 f32 [16][132]; later out f32
  u16*  hst = (u16*)Tst;                                // h bf16 [16][264] aliases Tst
  const long r0 = (long)blockIdx.x * 64 + wave * 16;
  const float* xbase = xln + r0 * D_;

  // softmax of cheb weights
  float c0 = chebw[0], c1 = chebw[1], c2 = chebw[2];
  float cm = fmaxf(c0, fmaxf(c1, c2));
  float e0 = expf(c0 - cm), e1 = expf(c1 - cm), e2 = expf(c2 - cm);
  float ei = 1.f / (e0 + e1 + e2);
  float w0 = e0 * ei, w1 = e1 * ei, w2 = e2 * ei;

  // ---- A: load X A-frags (row=ll, k=kf*32+g*8..+8), split hi/lo ----
  bf16x8_t ax_hi[4], ax_lo[4];
  #pragma unroll
  for (int kf = 0; kf < 4; kf++){
    const float* p = xbase + (long)ll * D_ + kf * 32 + g * 8;
    float v[8];
    *(f32x4_t*)&v[0] = *(const f32x4_t*)p;
    *(f32x4_t*)&v[4] = *(const f32x4_t*)(p + 4);
    split8(v, ax_hi[kf], ax_lo[kf]);
  }

  // ---- B: T1 = X @ Lap  (split bf16: hi*hi + lo*hi + hi*lo) ----
  f32x4_t acc1[8];
  #pragma unroll
  for (int ct = 0; ct < 8; ct++){
    f32x4_t a = {0.f, 0.f, 0.f, 0.f};
    #pragma unroll
    for (int kf = 0; kf < 4; kf++){
      bf16x8_t bh = *(const bf16x8_t*)(lapf_hi + ((ct * 4 + kf) * 64 + lane) * 8);
      bf16x8_t bl = *(const bf16x8_t*)(lapf_lo + ((ct * 4 + kf) * 64 + lane) * 8);
      a = __builtin_amdgcn_mfma_f32_16x16x32_bf16(ax_hi[kf], bh, a, 0, 0, 0);
      a = __builtin_amdgcn_mfma_f32_16x16x32_bf16(ax_lo[kf], bh, a, 0, 0, 0);
      a = __builtin_amdgcn_mfma_f32_16x16x32_bf16(ax_hi[kf], bl, a, 0, 0, 0);
    }
    acc1[ct] = a;
  }

  // ---- C: write T1 (acc layout: row=g*4+r, col=ct*16+ll) to Tst ----
  #pragma unroll
  for (int ct = 0; ct < 8; ct++)
    #pragma unroll
    for (int r = 0; r < 4; r++)
      Tst[(g * 4 + r) * 132 + ct * 16 + ll] = acc1[ct][r];

  // ---- D: T2acc = T1 @ Lap ----
  bf16x8_t at_hi[4], at_lo[4];
  #pragma unroll
  for (int kf = 0; kf < 4; kf++){
    float v[8];
    *(f32x4_t*)&v[0] = *(const f32x4_t*)&Tst[ll * 132 + kf * 32 + g * 8];
    *(f32x4_t*)&v[4] = *(const f32x4_t*)&Tst[ll * 132 + kf * 32 + g * 8 + 4];
    split8(v, at_hi[kf], at_lo[kf]);
  }
  f32x4_t acc2[8];
  #pragma unroll
  for (int ct = 0; ct < 8; ct++){
    f32x4_t a = {0.f, 0.f, 0.f, 0.f};
    #pragma unroll
    for (int kf = 0; kf < 4; kf++){
      bf16x8_t bh = *(const bf16x8_t*)(lapf_hi + ((ct * 4 + kf) * 64 + lane) * 8);
      bf16x8_t bl = *(const bf16x8_t*)(lapf_lo + ((ct * 4 + kf) * 64 + lane) * 8);
      a = __builtin_amdgcn_mfma_f32_16x16x32_bf16(at_hi[kf], bh, a, 0, 0, 0);
      a = __builtin_amdgcn_mfma_f32_16x16x32_bf16(at_lo[kf], bh, a, 0, 0, 0);
      a = __builtin_amdgcn_mfma_f32_16x16x32_bf16(at_hi[kf], bl, a, 0, 0, 0);
    }
    acc2[ct] = a;
  }

  // ---- E: re-read X (acc layout) from global; out = w0*X + w1*T1 + w2*clip;
  //         write out (f32) back over Tst. X loads double-buffered across r. ----
  {
    float xp0[8], xp1[8];
    #pragma unroll
    for (int ct = 0; ct < 8; ct++) xp0[ct] = xbase[(long)(g * 4 + 0) * D_ + ct * 16 + ll];
    #pragma unroll
    for (int r = 0; r < 4; r++){
      if (r < 3){
        if ((r & 1) == 0){
          #pragma unroll
          for (int ct = 0; ct < 8; ct++) xp1[ct] = xbase[(long)(g * 4 + r + 1) * D_ + ct * 16 + ll];
        } else {
          #pragma unroll
          for (int ct = 0; ct < 8; ct++) xp0[ct] = xbase[(long)(g * 4 + r + 1) * D_ + ct * 16 + ll];
        }
      }
      #pragma unroll
      for (int ct = 0; ct < 8; ct++){
        float Xv = ((r & 1) == 0) ? xp0[ct] : xp1[ct];
        float T2v = fminf(fmaxf(2.f * acc2[ct][r] - Xv, -50.f), 50.f);
        Tst[(g * 4 + r) * 132 + ct * 16 + ll] = w0 * Xv + w1 * acc1[ct][r] + w2 * T2v;
      }
    }
  }

  // ---- F: h = out @ Wi^T + bi ----
  bf16x8_t ao[4];
  #pragma unroll
  for (int kf = 0; kf < 4; kf++){
    float v[8];
    *(f32x4_t*)&v[0] = *(const f32x4_t*)&Tst[ll * 132 + kf * 32 + g * 8];
    *(f32x4_t*)&v[4] = *(const f32x4_t*)&Tst[ll * 132 + kf * 32 + g * 8 + 4];
    #pragma unroll
    for (int j = 0; j < 8; j++) ao[kf][j] = (short)f2bf(v[j]);
  }
  f32x4_t acch[16];
  #pragma unroll
  for (int ct = 0; ct < 16; ct++){
    f32x4_t a = {0.f, 0.f, 0.f, 0.f};
    #pragma unroll
    for (int kf = 0; kf < 4; kf++){
      bf16x8_t bw = *(const bf16x8_t*)(wif + ((ct * 4 + kf) * 64 + lane) * 8);
      a = __builtin_amdgcn_mfma_f32_16x16x32_bf16(ao[kf], bw, a, 0, 0, 0);
    }
    float biv = bi[ct * 16 + ll];
    #pragma unroll
    for (int r = 0; r < 4; r++) a[r] += biv;
    acch[ct] = a;
  }

  // ---- G: LN2 + exact gelu, stage h as bf16 [16][264] over same buffer ----
  #pragma unroll
  for (int r = 0; r < 4; r++){
    float s = 0.f, sq = 0.f;
    #pragma unroll
    for (int ct = 0; ct < 16; ct++){ float v = acch[ct][r]; s += v; sq += v * v; }
    #pragma unroll
    for (int m = 1; m < 16; m <<= 1){ s += __shfl_xor(s, m); sq += __shfl_xor(sq, m); }
    float mean = s * (1.f / (float)H_);
    float var  = sq * (1.f / (float)H_) - mean * mean;
    float rstd = rsqrtf(var + 1e-8f);
    #pragma unroll
    for (int ct = 0; ct < 16; ct++){
      int col = ct * 16 + ll;
      float v = (acch[ct][r] - mean) * rstd * g2[col] + b2[col];
      v = 0.5f * v * (1.f + erff(v * 0.70710678118f));
      hst[(g * 4 + r) * 264 + col] = f2bf(v);
    }
  }

  // ---- H: o = h @ Wo^T + bo (h A-frags read directly as bf16) ----
  bf16x8_t ah[8];
  #pragma unroll
  for (int kf = 0; kf < 8; kf++)
    ah[kf] = *(const bf16x8_t*)&hst[ll * 264 + kf * 32 + g * 8];
  f32x4_t acco[8];
  #pragma unroll
  for (int ct = 0; ct < 8; ct++){
    f32x4_t a = {0.f, 0.f, 0.f, 0.f};
    #pragma unroll
    for (int kf = 0; kf < 8; kf++){
      bf16x8_t bw = *(const bf16x8_t*)(wof + ((ct * 8 + kf) * 64 + lane) * 8);
      a = __builtin_amdgcn_mfma_f32_16x16x32_bf16(ah[kf], bw, a, 0, 0, 0);
    }
    float bov = bo[ct * 16 + ll];
    #pragma unroll
    for (int r = 0; r < 4; r++) a[r] += bov;
    acco[ct] = a;
  }

  // ---- I: LN3 + store to d_out (overwrites this block's xln rows - safe) ----
  #pragma unroll
  for (int r = 0; r < 4; r++){
    float s = 0.f, sq = 0.f;
    #pragma unroll
    for (int ct = 0; ct < 8; ct++){ float v = acco[ct][r]; s += v; sq += v * v; }
    #pragma unroll
    for (int m = 1; m < 16; m <<= 1){ s += __shfl_xor(s, m); sq += __shfl_xor(sq, m); }
    float mean = s * (1.f / (float)O_);
    float var  = sq * (1.f / (float)O_) - mean * mean;
    float rstd = rsqrtf(var + 1e-8f);
    long grow = r0 + g * 4 + r;
    #pragma unroll
    for (int ct = 0; ct < 8; ct++){
      int col = ct * 16 + ll;
      out[grow * O_ + col] = (acco[ct][r] - mean) * rstd * g3[col] + b3[col];
    }
  }
}

// ---------------- launch ----------------
extern "C" void kernel_launch(void* const* d_in, const int* in_sizes, int n_in,
                              void* d_out, int out_size, void* d_ws, size_t ws_size,
                              hipStream_t stream) {
  const float* x    = (const float*)d_in[0];
  const float* corr = (const float*)d_in[1];
  const float* alog = (const float*)d_in[2];
  const float* chw  = (const float*)d_in[3];
  const float* Wi   = (const float*)d_in[4];
  const float* bi   = (const float*)d_in[5];
  const float* Wo   = (const float*)d_in[6];
  const float* bo   = (const float*)d_in[7];
  const float* g1   = (const float*)d_in[8];
  const float* b1   = (const float*)d_in[9];
  const float* g2   = (const float*)d_in[10];
  const float* b2   = (const float*)d_in[11];
  const float* g3   = (const float*)d_in[12];
  const float* b3   = (const float*)d_in[13];

  float* outp      = (float*)d_out;
  float* xln       = outp;                 // o-region doubles as xln scratch (64 MB)
  float* mixed_out = outp + O_ELEMS;       // second output

  char* w = (char*)d_ws;                   // needs ~8.7 MB of ws
  float* colsum = (float*)(w + 0);         // 16 KB
  float* gram   = (float*)(w + 16384);     // 8 MB
  float* means  = (float*)(w + 8404992);
  float* norms  = (float*)(w + 8421376);
  float* deg    = (float*)(w + 8437760);
  u16* lapf_hi  = (u16*)(w + 8438272);
  u16* lapf_lo  = (u16*)(w + 8471040);
  u16* wif      = (u16*)(w + 8503808);
  u16* wof      = (u16*)(w + 8569344);

  (void)hipMemsetAsync(w, 0, 16384 + 8388608, stream);  // colsum + gram
  k_prepw <<<32, 256, 0, stream>>>(Wi, Wo, wif, wof);
  k_ln1   <<<NROWS/8, 256, 0, stream>>>(x, g1, b1, xln);
  k_gram  <<<B_*16, 256, 0, stream>>>(xln, gram, colsum);
  k_stats <<<B_, 128, 0, stream>>>(colsum, gram, means, norms);
  k_mixed <<<D_, 128, 0, stream>>>(gram, means, norms, corr, alog, mixed_out, deg);
  k_lap   <<<D_, 128, 0, stream>>>(mixed_out, deg, lapf_hi, lapf_lo);
  k_mega  <<<NROWS/64, 256, 0, stream>>>(xln, outp, lapf_hi, lapf_lo, wif, wof,
                                         bi, bo, g2, b2, g3, b3, chw);
}

// Round 8
// 379.416 us; speedup vs baseline: 1.4993x; 1.4993x over previous
//
#include <hip/hip_runtime.h>
#include <math.h>

#define B_ 32
#define L_ 4096
#define D_ 128
#define H_ 256
#define O_ 128
#define NROWS (B_*L_)          // 131072
#define O_ELEMS ((long)NROWS*O_)   // 16777216

typedef float f32x4_t __attribute__((ext_vector_type(4)));
typedef short bf16x8_t __attribute__((ext_vector_type(8)));
typedef unsigned short u16;

__device__ __forceinline__ u16 f2bf(float f){           // RNE f32 -> bf16 bits
  unsigned u = __float_as_uint(f);
  unsigned r = (u + 0x7FFFu + ((u >> 16) & 1u)) >> 16;
  return (u16)r;
}

__device__ __forceinline__ void split8(const float* v, bf16x8_t& hi, bf16x8_t& lo){
  #pragma unroll
  for (int j = 0; j < 8; j++){
    unsigned u = __float_as_uint(v[j]);
    hi[j] = (short)(u >> 16);                            // truncated high part (exact)
    lo[j] = (short)f2bf(v[j] - __uint_as_float(u & 0xFFFF0000u));
  }
}

// ---------------- LN1: x -> xln (xln aliases d_out o-region) ----------------
__global__ __launch_bounds__(256) void k_ln1(const float* __restrict__ x,
    const float* __restrict__ g1, const float* __restrict__ b1, float* __restrict__ xln){
  int t = threadIdx.x;
  int half = t >> 5, hl = t & 31;                       // 8 half-waves per block
  long row = (long)blockIdx.x * 8 + half;
  const float* xr = x + row * D_;
  f32x4_t v = *(const f32x4_t*)(xr + hl * 4);
  float s  = v[0] + v[1] + v[2] + v[3];
  float sq = v[0]*v[0] + v[1]*v[1] + v[2]*v[2] + v[3]*v[3];
  #pragma unroll
  for (int m = 1; m < 32; m <<= 1){ s += __shfl_xor(s, m); sq += __shfl_xor(sq, m); }
  float mean = s * (1.0f / 128.0f);
  float var  = sq * (1.0f / 128.0f) - mean * mean;
  float rstd = rsqrtf(var + 1e-8f);
  f32x4_t gg = *(const f32x4_t*)(g1 + hl * 4);
  f32x4_t bb = *(const f32x4_t*)(b1 + hl * 4);
  f32x4_t o;
  #pragma unroll
  for (int j = 0; j < 4; j++) o[j] = (v[j] - mean) * rstd * gg[j] + bb[j];
  *(f32x4_t*)(xln + row * D_ + hl * 4) = o;
}

// ---------------- per-batch partial gram + partial colsum (NO atomics) ------
// v3: 8 chunks of 512 rows (256 blocks, 2/CU). Each block stores its private
// 128x128 partial (plain coalesced stores) + [2][128] partial colsums.
__global__ __launch_bounds__(256, 2) void k_gram(const float* __restrict__ xln,
                                                 float* __restrict__ pgram,
                                                 float* __restrict__ pcs){
  __shared__ float xs[64][128];
  int t = threadIdx.x;
  int b = blockIdx.x >> 3, chunk = blockIdx.x & 7;      // 8 chunks of 512 rows
  const float* base = xln + ((long)b * L_ + (long)chunk * 512) * D_;
  int dr = (t >> 4) * 8, ec = (t & 15) * 8;
  int cc = t & 127, rlo = (t >> 7) * 32;                // colsum: 2 half-tiles of rows
  float cs = 0.f;
  float acc[8][8];
  #pragma unroll
  for (int i = 0; i < 8; i++)
    #pragma unroll
    for (int j = 0; j < 8; j++) acc[i][j] = 0.f;
  for (int sub = 0; sub < 8; sub++){
    __syncthreads();
    const float* src = base + (long)sub * 64 * D_;
    #pragma unroll
    for (int i = 0; i < 8; i++){
      int idx = t + i * 256;                            // 2048 float4 = 64x128 floats
      ((f32x4_t*)&xs[0][0])[idx] = ((const f32x4_t*)src)[idx];
    }
    __syncthreads();
    for (int l = 0; l < 64; l++){
      float a[8], c[8];
      #pragma unroll
      for (int i = 0; i < 8; i++){ a[i] = xs[l][dr + i]; c[i] = xs[l][ec + i]; }
      #pragma unroll
      for (int i = 0; i < 8; i++)
        #pragma unroll
        for (int j = 0; j < 8; j++) acc[i][j] += a[i] * c[j];
    }
    for (int l = rlo; l < rlo + 32; l++) cs += xs[l][cc];
  }
  float* gb = pgram + (long)blockIdx.x * (D_ * D_);
  #pragma unroll
  for (int i = 0; i < 8; i++)
    #pragma unroll
    for (int j = 0; j < 4; j++)
      *(float2*)&gb[(dr + i) * D_ + ec + j * 2] = make_float2(acc[i][j*2], acc[i][j*2+1]);
  pcs[blockIdx.x * 256 + t] = cs;                       // [block][half][128]
}

// ---------------- reduce partials -> gram; diag threads -> means/norms ------
__global__ __launch_bounds__(256) void k_reduce(const float* __restrict__ pgram,
    const float* __restrict__ pcs, float* __restrict__ gram,
    float* __restrict__ means, float* __restrict__ norms){
  int b = blockIdx.x >> 6;                              // 32 batches x 64 blocks
  long e0 = ((long)(blockIdx.x & 63)) * 256 + threadIdx.x;   // elem in [0,16384)
  float s = 0.f;
  #pragma unroll
  for (int c = 0; c < 8; c++) s += pgram[((long)(b * 8 + c)) * 16384 + e0];
  gram[(long)b * 16384 + e0] = s;
  int d = (int)(e0 >> 7), e = (int)(e0 & 127);
  if (d == e){
    float csum = 0.f;
    #pragma unroll
    for (int c = 0; c < 16; c++)
      csum += pcs[(b * 8 + (c >> 1)) * 256 + (c & 1) * 128 + d];
    float m = csum * (1.0f / (float)L_);
    float cov = fmaxf(s - (float)L_ * m * m, 0.f);
    means[b * D_ + d] = m;
    norms[b * D_ + d] = fmaxf(sqrtf(cov), 1e-8f);
  }
}

// ---------------- mixed correlation (output 1) + degree vector ----------------
__global__ __launch_bounds__(128) void k_mixed(const float* __restrict__ gram,
    const float* __restrict__ means, const float* __restrict__ norms,
    const float* __restrict__ corr, const float* __restrict__ alpha_logit,
    float* __restrict__ mixed_out, float* __restrict__ deg){
  int d = blockIdx.x, e = threadIdx.x;
  float s = 0.f;
  for (int b = 0; b < B_; b++){
    float cov = gram[((long)b * D_ + d) * D_ + e]
              - (float)L_ * means[b * D_ + d] * means[b * D_ + e];
    s += cov / (norms[b * D_ + d] * norms[b * D_ + e]);
  }
  float dc = fminf(fmaxf(s * (1.0f / (float)B_), -1.f), 1.f);
  float learned = tanhf(0.5f * (corr[d * D_ + e] + corr[e * D_ + d]));
  float alpha = 1.f / (1.f + expf(-alpha_logit[0]));
  float mx = alpha * learned + (1.f - alpha) * dc;
  mixed_out[d * D_ + e] = mx;
  float a = (d == e) ? 0.f : mx;
  __shared__ float red[128];
  red[e] = a; __syncthreads();
  for (int st = 64; st > 0; st >>= 1){
    if (e < st) red[e] += red[e + st];
    __syncthreads();
  }
  if (e == 0) deg[d] = red[0];
}

// ---------------- Laplacian -> fragment-ordered bf16 hi/lo ----------------
__global__ __launch_bounds__(128) void k_lap(const float* __restrict__ mixed_out,
    const float* __restrict__ deg, u16* __restrict__ lapf_hi, u16* __restrict__ lapf_lo){
  int d = blockIdx.x, e = threadIdx.x;                  // Lap row d (k-index), col e
  float dis_d = rsqrtf(fmaxf(deg[d], 1e-8f));
  float dis_e = rsqrtf(fmaxf(deg[e], 1e-8f));
  float A = (d == e) ? 0.f : mixed_out[d * D_ + e];
  float lv = ((d == e) ? 1.f : 0.f) - dis_d * A * dis_e;
  lv = fminf(fmaxf(lv, -1.5f), 1.5f);
  // B-fragment position for mfma_f32_16x16x32_bf16: col=ct*16+(lane&15), k=kf*32+(lane>>4)*8+j
  int ct = e >> 4, llw = e & 15;
  int kf = d >> 5, g = (d >> 3) & 3, j = d & 7;
  long idx = (((long)(ct * 4 + kf)) * 64 + (g * 16 + llw)) * 8 + j;
  unsigned u = __float_as_uint(lv);
  lapf_hi[idx] = (u16)(u >> 16);
  lapf_lo[idx] = f2bf(lv - __uint_as_float(u & 0xFFFF0000u));
}

// ---------------- Wi / Wo -> fragment-ordered plain bf16 ----------------
__global__ void k_prepw(const float* __restrict__ Wi, const float* __restrict__ Wo,
                        u16* __restrict__ wif, u16* __restrict__ wof){
  int tid = blockIdx.x * 256 + threadIdx.x;             // 8192 total
  if (tid < 4096){                                      // Wi: ct(16) kf(4) lane(64)
    int lane = tid & 63, kf = (tid >> 6) & 3, ct = tid >> 8;
    int row = ct * 16 + (lane & 15);
    int k0 = kf * 32 + (lane >> 4) * 8;
    #pragma unroll
    for (int j = 0; j < 8; j++) wif[tid * 8 + j] = f2bf(Wi[row * D_ + k0 + j]);
  } else {                                              // Wo: ct(8) kf(8) lane(64)
    int t = tid - 4096;
    int lane = t & 63, kf = (t >> 6) & 7, ct = t >> 9;
    int row = ct * 16 + (lane & 15);
    int k0 = kf * 32 + (lane >> 4) * 8;
    #pragma unroll
    for (int j = 0; j < 8; j++) wof[t * 8 + j] = f2bf(Wo[row * H_ + k0 + j]);
  }
}

// ---------------- fused Cheb + proj + LN2/gelu + LN3 ----------------
// 8.25 KB LDS/wave (union of Tst f32[16][132] and h bf16[16][264]); 4 blocks/CU.
__global__ __launch_bounds__(256, 4) void k_mega(
    const float* xln, float* out,                       // ALIAS (same buffer) - no restrict
    const u16* __restrict__ lapf_hi, const u16* __restrict__ lapf_lo,
    const u16* __restrict__ wif, const u16* __restrict__ wof,
    const float* __restrict__ bi, const float* __restrict__ bo,
    const float* __restrict__ g2, const float* __restrict__ b2,
    const float* __restrict__ g3, const float* __restrict__ b3,
    const float* __restrict__ chebw)
{
  __shared__ float smem[4][2112];                       // 8448 B per wave
  const int wave = threadIdx.x >> 6, lane = threadIdx.x & 63;
  const int ll = lane & 15, g = lane >> 4;
  float* Tst = &smem[wave][0];                          // T1 f32 [16][132]; later out f32
  u16*  hst = (u16*)Tst;                                // h bf16 [16][264] aliases Tst
  const long r0 = (long)blockIdx.x * 64 + wave * 16;
  const float* xbase = xln + r0 * D_;

  // softmax of cheb weights
  float c0 = chebw[0], c1 = chebw[1], c2 = chebw[2];
  float cm = fmaxf(c0, fmaxf(c1, c2));
  float e0 = expf(c0 - cm), e1 = expf(c1 - cm), e2 = expf(c2 - cm);
  float ei = 1.f / (e0 + e1 + e2);
  float w0 = e0 * ei, w1 = e1 * ei, w2 = e2 * ei;

  // ---- A: load X A-frags (row=ll, k=kf*32+g*8..+8), split hi/lo ----
  bf16x8_t ax_hi[4], ax_lo[4];
  #pragma unroll
  for (int kf = 0; kf < 4; kf++){
    const float* p = xbase + (long)ll * D_ + kf * 32 + g * 8;
    float v[8];
    *(f32x4_t*)&v[0] = *(const f32x4_t*)p;
    *(f32x4_t*)&v[4] = *(const f32x4_t*)(p + 4);
    split8(v, ax_hi[kf], ax_lo[kf]);
  }

  // ---- B: T1 = X @ Lap  (split bf16: hi*hi + lo*hi + hi*lo) ----
  f32x4_t acc1[8];
  #pragma unroll
  for (int ct = 0; ct < 8; ct++){
    f32x4_t a = {0.f, 0.f, 0.f, 0.f};
    #pragma unroll
    for (int kf = 0; kf < 4; kf++){
      bf16x8_t bh = *(const bf16x8_t*)(lapf_hi + ((ct * 4 + kf) * 64 + lane) * 8);
      bf16x8_t bl = *(const bf16x8_t*)(lapf_lo + ((ct * 4 + kf) * 64 + lane) * 8);
      a = __builtin_amdgcn_mfma_f32_16x16x32_bf16(ax_hi[kf], bh, a, 0, 0, 0);
      a = __builtin_amdgcn_mfma_f32_16x16x32_bf16(ax_lo[kf], bh, a, 0, 0, 0);
      a = __builtin_amdgcn_mfma_f32_16x16x32_bf16(ax_hi[kf], bl, a, 0, 0, 0);
    }
    acc1[ct] = a;
  }

  // ---- C: write T1 (acc layout: row=g*4+r, col=ct*16+ll) to Tst ----
  #pragma unroll
  for (int ct = 0; ct < 8; ct++)
    #pragma unroll
    for (int r = 0; r < 4; r++)
      Tst[(g * 4 + r) * 132 + ct * 16 + ll] = acc1[ct][r];

  // ---- D: T2acc = T1 @ Lap ----
  bf16x8_t at_hi[4], at_lo[4];
  #pragma unroll
  for (int kf = 0; kf < 4; kf++){
    float v[8];
    *(f32x4_t*)&v[0] = *(const f32x4_t*)&Tst[ll * 132 + kf * 32 + g * 8];
    *(f32x4_t*)&v[4] = *(const f32x4_t*)&Tst[ll * 132 + kf * 32 + g * 8 + 4];
    split8(v, at_hi[kf], at_lo[kf]);
  }
  f32x4_t acc2[8];
  #pragma unroll
  for (int ct = 0; ct < 8; ct++){
    f32x4_t a = {0.f, 0.f, 0.f, 0.f};
    #pragma unroll
    for (int kf = 0; kf < 4; kf++){
      bf16x8_t bh = *(const bf16x8_t*)(lapf_hi + ((ct * 4 + kf) * 64 + lane) * 8);
      bf16x8_t bl = *(const bf16x8_t*)(lapf_lo + ((ct * 4 + kf) * 64 + lane) * 8);
      a = __builtin_amdgcn_mfma_f32_16x16x32_bf16(at_hi[kf], bh, a, 0, 0, 0);
      a = __builtin_amdgcn_mfma_f32_16x16x32_bf16(at_lo[kf], bh, a, 0, 0, 0);
      a = __builtin_amdgcn_mfma_f32_16x16x32_bf16(at_hi[kf], bl, a, 0, 0, 0);
    }
    acc2[ct] = a;
  }

  // ---- E: re-read X (acc layout) from global; out = w0*X + w1*T1 + w2*clip;
  //         write out (f32) back over Tst. X loads double-buffered across r. ----
  {
    float xp0[8], xp1[8];
    #pragma unroll
    for (int ct = 0; ct < 8; ct++) xp0[ct] = xbase[(long)(g * 4 + 0) * D_ + ct * 16 + ll];
    #pragma unroll
    for (int r = 0; r < 4; r++){
      if (r < 3){
        if ((r & 1) == 0){
          #pragma unroll
          for (int ct = 0; ct < 8; ct++) xp1[ct] = xbase[(long)(g * 4 + r + 1) * D_ + ct * 16 + ll];
        } else {
          #pragma unroll
          for (int ct = 0; ct < 8; ct++) xp0[ct] = xbase[(long)(g * 4 + r + 1) * D_ + ct * 16 + ll];
        }
      }
      #pragma unroll
      for (int ct = 0; ct < 8; ct++){
        float Xv = ((r & 1) == 0) ? xp0[ct] : xp1[ct];
        float T2v = fminf(fmaxf(2.f * acc2[ct][r] - Xv, -50.f), 50.f);
        Tst[(g * 4 + r) * 132 + ct * 16 + ll] = w0 * Xv + w1 * acc1[ct][r] + w2 * T2v;
      }
    }
  }

  // ---- F: h = out @ Wi^T + bi ----
  bf16x8_t ao[4];
  #pragma unroll
  for (int kf = 0; kf < 4; kf++){
    float v[8];
    *(f32x4_t*)&v[0] = *(const f32x4_t*)&Tst[ll * 132 + kf * 32 + g * 8];
    *(f32x4_t*)&v[4] = *(const f32x4_t*)&Tst[ll * 132 + kf * 32 + g * 8 + 4];
    #pragma unroll
    for (int j = 0; j < 8; j++) ao[kf][j] = (short)f2bf(v[j]);
  }
  f32x4_t acch[16];
  #pragma unroll
  for (int ct = 0; ct < 16; ct++){
    f32x4_t a = {0.f, 0.f, 0.f, 0.f};
    #pragma unroll
    for (int kf = 0; kf < 4; kf++){
      bf16x8_t bw = *(const bf16x8_t*)(wif + ((ct * 4 + kf) * 64 + lane) * 8);
      a = __builtin_amdgcn_mfma_f32_16x16x32_bf16(ao[kf], bw, a, 0, 0, 0);
    }
    float biv = bi[ct * 16 + ll];
    #pragma unroll
    for (int r = 0; r < 4; r++) a[r] += biv;
    acch[ct] = a;
  }

  // ---- G: LN2 + exact gelu, stage h as bf16 [16][264] over same buffer ----
  #pragma unroll
  for (int r = 0; r < 4; r++){
    float s = 0.f, sq = 0.f;
    #pragma unroll
    for (int ct = 0; ct < 16; ct++){ float v = acch[ct][r]; s += v; sq += v * v; }
    #pragma unroll
    for (int m = 1; m < 16; m <<= 1){ s += __shfl_xor(s, m); sq += __shfl_xor(sq, m); }
    float mean = s * (1.f / (float)H_);
    float var  = sq * (1.f / (float)H_) - mean * mean;
    float rstd = rsqrtf(var + 1e-8f);
    #pragma unroll
    for (int ct = 0; ct < 16; ct++){
      int col = ct * 16 + ll;
      float v = (acch[ct][r] - mean) * rstd * g2[col] + b2[col];
      v = 0.5f * v * (1.f + erff(v * 0.70710678118f));
      hst[(g * 4 + r) * 264 + col] = f2bf(v);
    }
  }

  // ---- H: o = h @ Wo^T + bo (h A-frags read directly as bf16) ----
  bf16x8_t ah[8];
  #pragma unroll
  for (int kf = 0; kf < 8; kf++)
    ah[kf] = *(const bf16x8_t*)&hst[ll * 264 + kf * 32 + g * 8];
  f32x4_t acco[8];
  #pragma unroll
  for (int ct = 0; ct < 8; ct++){
    f32x4_t a = {0.f, 0.f, 0.f, 0.f};
    #pragma unroll
    for (int kf = 0; kf < 8; kf++){
      bf16x8_t bw = *(const bf16x8_t*)(wof + ((ct * 8 + kf) * 64 + lane) * 8);
      a = __builtin_amdgcn_mfma_f32_16x16x32_bf16(ah[kf], bw, a, 0, 0, 0);
    }
    float bov = bo[ct * 16 + ll];
    #pragma unroll
    for (int r = 0; r < 4; r++) a[r] += bov;
    acco[ct] = a;
  }

  // ---- I: LN3 + store to d_out (overwrites this block's xln rows - safe) ----
  #pragma unroll
  for (int r = 0; r < 4; r++){
    float s = 0.f, sq = 0.f;
    #pragma unroll
    for (int ct = 0; ct < 8; ct++){ float v = acco[ct][r]; s += v; sq += v * v; }
    #pragma unroll
    for (int m = 1; m < 16; m <<= 1){ s += __shfl_xor(s, m); sq += __shfl_xor(sq, m); }
    float mean = s * (1.f / (float)O_);
    float var  = sq * (1.f / (float)O_) - mean * mean;
    float rstd = rsqrtf(var + 1e-8f);
    long grow = r0 + g * 4 + r;
    #pragma unroll
    for (int ct = 0; ct < 8; ct++){
      int col = ct * 16 + ll;
      out[grow * O_ + col] = (acco[ct][r] - mean) * rstd * g3[col] + b3[col];
    }
  }
}

// ---------------- launch ----------------
extern "C" void kernel_launch(void* const* d_in, const int* in_sizes, int n_in,
                              void* d_out, int out_size, void* d_ws, size_t ws_size,
                              hipStream_t stream) {
  const float* x    = (const float*)d_in[0];
  const float* corr = (const float*)d_in[1];
  const float* alog = (const float*)d_in[2];
  const float* chw  = (const float*)d_in[3];
  const float* Wi   = (const float*)d_in[4];
  const float* bi   = (const float*)d_in[5];
  const float* Wo   = (const float*)d_in[6];
  const float* bo   = (const float*)d_in[7];
  const float* g1   = (const float*)d_in[8];
  const float* b1   = (const float*)d_in[9];
  const float* g2   = (const float*)d_in[10];
  const float* b2   = (const float*)d_in[11];
  const float* g3   = (const float*)d_in[12];
  const float* b3   = (const float*)d_in[13];

  float* outp      = (float*)d_out;
  float* xln       = outp;                 // o-region doubles as xln scratch (64 MB)
  float* mixed_out = outp + O_ELEMS;       // second output

  char* w = (char*)d_ws;                   // ~25.7 MB of ws
  float* pgram  = (float*)(w + 0);                 // 256*16384*4 = 16 MB
  float* pcs    = (float*)(w + 16777216);          // 256*256*4 = 256 KB
  float* gram   = (float*)(w + 17039360);          // 8 MB
  float* means  = (float*)(w + 25427968);
  float* norms  = (float*)(w + 25444352);
  float* deg    = (float*)(w + 25460736);
  u16* lapf_hi  = (u16*)(w + 25461248);
  u16* lapf_lo  = (u16*)(w + 25494016);
  u16* wif      = (u16*)(w + 25526784);
  u16* wof      = (u16*)(w + 25592320);

  k_prepw <<<32, 256, 0, stream>>>(Wi, Wo, wif, wof);
  k_ln1   <<<NROWS/8, 256, 0, stream>>>(x, g1, b1, xln);
  k_gram  <<<B_*8, 256, 0, stream>>>(xln, pgram, pcs);
  k_reduce<<<B_*64, 256, 0, stream>>>(pgram, pcs, gram, means, norms);
  k_mixed <<<D_, 128, 0, stream>>>(gram, means, norms, corr, alog, mixed_out, deg);
  k_lap   <<<D_, 128, 0, stream>>>(mixed_out, deg, lapf_hi, lapf_lo);
  k_mega  <<<NROWS/64, 256, 0, stream>>>(xln, outp, lapf_hi, lapf_lo, wif, wof,
                                         bi, bo, g2, b2, g3, b3, chw);
}